// Round 12
// baseline (64.246 us; speedup 1.0000x reference)
//
#include <hip/hip_runtime.h>
#include <hip/hip_bf16.h>

// FlowNet correlation via bf16 MFMA (gfx950).
// out[b, p*9+o, y, x] = (1/128) sum_c f[b,c,y,x] * s[b,c,y+p-4,x+o-4], zero-pad.
//
// Round 12 = round 11 + prefetch distance 2 (ONLY change). r11 post-mortem:
// no pipe >25% busy; all waves convoy at write_lds's vmcnt wait (distance-1
// slack ~800 cyc < congested mem latency). Two pv register sets, k-loop
// statically unrolled (rule #20): pv(k) consumed 2 full phases after issue.
// Tile (b, 4y, 16x), 2048 blocks x 512 thr, LDS 35.8 KB, 2 blocks/CU.

namespace {
constexpr int kC = 128, kH = 128, kW = 256;
constexpr int kWin = 9;
constexpr int kYB = 4, kXB = 16;
constexpr int kSR = kYB + 8;                      // 12 s-rows
constexpr int kSX = kXB + 16;                     // 32 s-cols (x' span)
constexpr int kCP = 40;                           // c-stride (entries), 16B-aligned
constexpr int kKC = 32;                           // channels per chunk
constexpr int kNK = kC / kKC;                     // 4
constexpr int kSSz = kSR * kSX * kCP;             // 15360 entries
constexpr int kFSz = kYB * kXB * kCP;             // 2560
constexpr int kLdsE = kSSz + kFSz;                // 17920 entries = 35840 B
constexpr int kSU = kSR * (kSX / 4) * (kKC / 8);  // 384 s staging units
constexpr int kFU = kYB * (kXB / 4) * (kKC / 8);  // 64 f staging units
constexpr int kTU = kSU + kFU;                    // 448 (<= 512, 1/thread)
constexpr int kThreads = 512;                     // 8 waves
constexpr int kBlocks = 4 * (kH / kYB) * (kW / kXB);  // 2048
constexpr int kOS = kYB * kXB + 4;                // 68: OUT_lds per-d stride
constexpr int kCStr = kH * kW;                    // 32768

typedef __attribute__((ext_vector_type(8))) short bf16x8;
typedef __attribute__((ext_vector_type(4))) float f32x4;
}  // namespace

__global__ __launch_bounds__(kThreads, 4) void corr_mfma(
    const float* __restrict__ first,
    const float* __restrict__ second,
    float* __restrict__ out)
{
    __shared__ __align__(16) unsigned short lds[kLdsE];   // 35.8 KB

    const int tid  = threadIdx.x;
    const int lane = tid & 63;
    const int wid  = tid >> 6;          // 0..7
    const int yslot = wid >> 1;         // 0..3
    const int Ns    = wid & 1;          // N-half 0/1

    // XCD-grouped bijective swizzle: 2048 = 8 xcd x 256.
    const int bid = blockIdx.x;
    const int xcd = bid & 7;
    const int seq = bid >> 3;           // 0..255
    const int xt  = seq & 15;
    const int g   = ((seq >> 4) << 3) + xcd;   // 0..127 = (b, y-stripe)
    const int b   = g >> 5;
    const int y0  = (g & 31) * kYB;
    const int X0  = xt * kXB;

    const size_t ibase = (size_t)b * kC * kCStr;

    // ---- staging role: ONE unit per thread (tid < 448) ----
    // unit = (row, x-quad, channel-octet): 8 float4 loads -> 16 cvt_pk -> 4 b128
    const float* ug = nullptr;
    int ul = -1;
    if (tid < kSU) {
        int co = tid & 3, xq = (tid >> 2) & 7, row = tid >> 5;
        int yg = y0 - 4 + row, xg = X0 - 8 + xq * 4;
        ul = (row * kSX + xq * 4) * kCP + co * 8;
        if (yg >= 0 && yg < kH && xg >= 0 && xg <= kW - 4)
            ug = second + ibase + (size_t)(co * 8) * kCStr + (size_t)yg * kW + xg;
    } else if (tid < kTU) {
        int u2 = tid - kSU;
        int co = u2 & 3, xq = (u2 >> 2) & 3, row = u2 >> 4;
        ul = kSSz + (row * kXB + xq * 4) * kCP + co * 8;
        ug = first + ibase + (size_t)(co * 8) * kCStr
                   + (size_t)(y0 + row) * kW + (X0 + xq * 4);
    }

    float4 pvA[8], pvB[8];
    auto issue = [&](float4* pv, int kc) {
        if (ul < 0) return;
        const float4 z = make_float4(0.f, 0.f, 0.f, 0.f);
#pragma unroll
        for (int j = 0; j < 8; ++j) pv[j] = z;
        if (ug) {
            const float* gp = ug + (size_t)kc * kKC * kCStr;
#pragma unroll
            for (int j = 0; j < 8; ++j)
                pv[j] = *(const float4*)(gp + (size_t)j * kCStr);
        }
    };
    auto write_lds = [&](const float4* pv) {
        if (ul < 0) return;
#pragma unroll
        for (int xi = 0; xi < 4; ++xi) {
            union { uint4 q; __hip_bfloat162 h[4]; } pk;
#pragma unroll
            for (int jj = 0; jj < 4; ++jj) {
                float lo = ((const float*)&pv[2 * jj])[xi];
                float hi = ((const float*)&pv[2 * jj + 1])[xi];
                pk.h[jj] = __float22bfloat162_rn(make_float2(lo, hi));
            }
            *(uint4*)&lds[ul + xi * kCP] = pk.q;
        }
    };

    // ---- compute-side fragment offsets ----
    const int l15 = lane & 15, lg = lane >> 4;
    const int aoff = kSSz + (yslot * kXB + l15) * kCP + lg * 8;
    const int boff = (yslot * kSX + Ns * 16 + l15) * kCP + lg * 8;

    f32x4 acc[kWin];
    {
        f32x4 z = {0.f, 0.f, 0.f, 0.f};
#pragma unroll
        for (int p = 0; p < kWin; ++p) acc[p] = z;
    }

    auto compute = [&]() {
        bf16x8 a = *(const bf16x8*)&lds[aoff];
#pragma unroll
        for (int p = 0; p < kWin; ++p) {
            bf16x8 bb = *(const bf16x8*)&lds[boff + p * (kSX * kCP)];
            acc[p] = __builtin_amdgcn_mfma_f32_16x16x32_bf16(a, bb, acc[p], 0, 0, 0);
        }
    };

    // ---- K loop: distance-2 prefetch, fully static (kNK == 4) ----
    issue(pvA, 0);
    issue(pvB, 1);
    // chunk 0
    write_lds(pvA);
    issue(pvA, 2);
    __syncthreads();
    compute();
    __syncthreads();
    // chunk 1
    write_lds(pvB);
    issue(pvB, 3);
    __syncthreads();
    compute();
    __syncthreads();
    // chunk 2
    write_lds(pvA);
    __syncthreads();
    compute();
    __syncthreads();
    // chunk 3
    write_lds(pvB);
    __syncthreads();
    compute();
    __syncthreads();

    // ---- epilogue: band-extract to OUT_lds (aliases staging), store ----
    float* outb = (float*)lds;
    const float inv = 1.0f / (float)kC;
    const int delta = Ns ? 12 : -4;
#pragma unroll
    for (int p = 0; p < kWin; ++p)
#pragma unroll
        for (int r = 0; r < 4; ++r) {
            int m = (lg << 2) + r;
            int o = l15 - m + delta;
            if (o >= 0 && o < kWin) {
                int d = p * kWin + o;
                outb[d * kOS + yslot * kXB + m] = acc[p][r] * inv;
            }
        }
    __syncthreads();

    const size_t ob = (size_t)b * (kWin * kWin) * kCStr;
    for (int i = tid; i < kWin * kWin * kYB * (kXB / 4); i += kThreads) {
        int d  = i >> 4;                 // 16 float4 per d (4y x 4xq)
        int r2 = i & 15;
        int yy = r2 >> 2, xq = r2 & 3;
        float4 v = *(const float4*)&outb[d * kOS + yy * kXB + xq * 4];
        *(float4*)&out[ob + ((size_t)d * kH + (y0 + yy)) * kW + X0 + xq * 4] = v;
    }
}

extern "C" void kernel_launch(void* const* d_in, const int* in_sizes, int n_in,
                              void* d_out, int out_size, void* d_ws, size_t ws_size,
                              hipStream_t stream) {
    const float* first  = (const float*)d_in[0];
    const float* second = (const float*)d_in[1];
    float* out = (float*)d_out;
    dim3 grid(kBlocks);      // 2048 blocks
    dim3 block(kThreads);    // 512 threads = 8 waves
    hipLaunchKernelGGL(corr_mfma, grid, block, 0, stream, first, second, out);
}